// Round 2
// baseline (1467.540 us; speedup 1.0000x reference)
//
#include <hip/hip_runtime.h>
#include <hip/hip_bf16.h>

// Problem constants (from reference): B=64, NCLS=200 -> BN rows = 12800
#define BROWS  12800
#define TSTEPS 8
#define EMB    300
#define EMBP   384          // EMB padded to /128 so K1 has an EVEN tile count
#define RNN    512
#define NG     2048         // 4*RNN gate width
#define K1     896          // EMBP + RNN  (layer-1 concat GEMM K), 14 tiles (even)
#define K2     1024         // RNN + RNN   (layer-2 concat GEMM K), 16 tiles (even)

typedef short bf16x8 __attribute__((ext_vector_type(8)));   // 8 bf16 in 4 VGPRs
typedef float f32x4  __attribute__((ext_vector_type(4)));
typedef __hip_bfloat16 bf16;

__device__ __forceinline__ float sigmoidf_(float x) { return 1.f / (1.f + __expf(-x)); }
__device__ __forceinline__ float tanhf_(float x)    { return 1.f - 2.f / (__expf(2.f * x) + 1.f); }

// async global->LDS, 16B per lane. LDS dest = wave-uniform base + lane*16.
__device__ __forceinline__ void gl_lds16(const bf16* g, bf16* l) {
    __builtin_amdgcn_global_load_lds(
        (const __attribute__((address_space(1))) void*)g,
        (__attribute__((address_space(3))) void*)l,
        16, 0, 0);
}

// ---------------------------------------------------------------------------
// Weight repack: fp32 -> bf16, K-concat LINEAR row-major [N=2048][K],
// GATE-INTERLEAVED row permutation: output row n encodes
//   w = n&15 (unit), g = (n>>4)&3 (gate i,f,g,o), b = n>>6 (unit group)
//   original row = g*512 + b*16 + w
// => each wave's 64-col span = [i|f|g|o] of the same 16 units.
// K1 layout: k<300 = Wih1, 300<=k<384 = zero pad, k>=384 = Whh1[k-384].
// ---------------------------------------------------------------------------
__global__ void convert_weights(const float* __restrict__ Wih1, const float* __restrict__ Whh1,
                                const float* __restrict__ Wih2, const float* __restrict__ Whh2,
                                const float* __restrict__ bih1, const float* __restrict__ bhh1,
                                const float* __restrict__ bih2, const float* __restrict__ bhh2,
                                bf16* __restrict__ Wc1, bf16* __restrict__ Wc2,
                                float* __restrict__ Bp1, float* __restrict__ Bp2) {
    int idx = blockIdx.x * 256 + threadIdx.x;
    const int n1 = NG * K1;   // 1,835,008
    const int n2 = NG * K2;   // 2,097,152
    if (idx < n1) {
        int n = idx / K1, k = idx - n * K1;
        int on = ((n >> 4) & 3) * RNN + (n >> 6) * 16 + (n & 15);
        float v = 0.f;
        if (k < EMB)        v = Wih1[on * EMB + k];
        else if (k >= EMBP) v = Whh1[on * RNN + (k - EMBP)];
        Wc1[idx] = __float2bfloat16(v);
    }
    if (idx < n2) {
        int n = idx >> 10, k = idx & (K2 - 1);
        int on = ((n >> 4) & 3) * RNN + (n >> 6) * 16 + (n & 15);
        float v = (k < RNN) ? Wih2[on * RNN + k] : Whh2[on * RNN + (k - RNN)];
        Wc2[idx] = __float2bfloat16(v);
    }
    if (idx < NG) {
        int on = ((idx >> 4) & 3) * RNN + (idx >> 6) * 16 + (idx & 15);
        Bp1[idx] = bih1[on] + bhh1[on];
        Bp2[idx] = bih2[on] + bhh2[on];
    }
}

// ---------------------------------------------------------------------------
// Embedding gather + tanh -> Xbuf [BROWS][384] (cols 300..383 zero pad).
// ---------------------------------------------------------------------------
__global__ void embed_step(const int* __restrict__ sent, const float* __restrict__ w2v,
                           bf16* __restrict__ Xbuf, int t) {
    int row = blockIdx.x;
    int col = threadIdx.x;                 // 0..383
    int id  = sent[row * TSTEPS + t];
    float v = (col < EMB) ? tanhf_(w2v[id * EMB + col]) : 0.f;
    Xbuf[(size_t)row * EMBP + col] = __float2bfloat16(v);
}

// ---------------------------------------------------------------------------
// ROUND-9: faithful m201 8-phase/2-tile schedule.
//
// Geometry: 512 thr = 8 waves (2M x 4N); wave tile 128x64; BK=64;
// LDS 128 KiB = 2 parity x (A[2x128][64] + B[2x128][64]) bf16.
// Quadrant order per tile: (m0n0),(m0n1),(m1n0),(m1n1); 16 MFMA each.
// Reads/tile: ph1=12 (A0-3,B0-1), ph2=4 (B2-3), ph3=8 (A4-7), ph4=0.
// All ds_reads are imm-offset off 8 precomputed base VGPRs (parity is a
// compile-time constant inside the 2-tile iteration) -> ~zero loop VALU.
//
// Staging (2 x gl_lds16 per phase, one 128-row half-tile), iter i reads
// tiles u=2i (p0), u+1 (p1):
//   ph1: A-lo(u+1)   [p1 A last read prev ph7, confirmed by its bar]
//   ph2: A-hi(u+1)
//   ph3: B-lo(u+2)   [p0 B consumed after ph2's lgkm0+bar]
//   ph4: B-hi(u+2); vmcnt(4) -> confirms A(u+1),B(u+1) before ph5 reads
//   ph5: A-lo(u+2)   [p0 A consumed after ph3]
//   ph6: A-hi(u+2)
//   ph7: B-lo(u+3)   [p1 B consumed after ph6]
//   ph8: B-hi(u+3); vmcnt(4) -> confirms A(u+2),B(u+2) before next ph1
// vmcnt(4) leaves exactly the 2 newest half-tiles (4 loads) in flight —
// never drains to 0 mid-loop (T4). Last iter: ph3-8 stage nothing,
// ph4 uses vmcnt(0) to confirm A(NT-1) staged at ph1/2.
// Prologue: A(0),B(0),B(1) staged (12 loads); vmcnt(4) confirms tile 0.
//
// Per-phase cadence (T3+T5): reads+stage, BAR, lgkm(0)+sched_barrier
// (rule #18), setprio(1), 16-MFMA pure burst, setprio(0), [vmcnt], BAR.
//
// Epilogue: unchanged round-3 fused LSTM (passed), h via LDS transpose
// (stride 72) for coalesced 16B stores.
// T1: bijective XCD swizzle over 400 blocks (400%8==0).
// ---------------------------------------------------------------------------
#define BM 256
#define BN 256

#define BAR()   __builtin_amdgcn_s_barrier()
#define SP1     __builtin_amdgcn_s_setprio(1)
#define SP0     __builtin_amdgcn_s_setprio(0)
#define LGKM0() do { asm volatile("s_waitcnt lgkmcnt(0)" ::: "memory"); \
                     __builtin_amdgcn_sched_barrier(0); } while (0)
#define VMC(n)  do { asm volatile("s_waitcnt vmcnt(" #n ")" ::: "memory"); \
                     __builtin_amdgcn_sched_barrier(0); } while (0)

// ds_read fragment groups (constant par/idx -> imm-offset ds_read_b128)
#define DSA(h2, par) do { _Pragma("unroll") for (int i2 = 0; i2 < 4; ++i2) \
    _Pragma("unroll") for (int kk2 = 0; kk2 < 2; ++kk2) \
        af[(h2)*4+i2][kk2] = *(const bf16x8*)(adrA[par][kk2] + ((h2)*4+i2)*1024); } while (0)
#define DSB(h2, par) do { _Pragma("unroll") for (int j2 = 0; j2 < 2; ++j2) \
    _Pragma("unroll") for (int kk2 = 0; kk2 < 2; ++kk2) \
        bfr[(h2)*2+j2][kk2] = *(const bf16x8*)(adrB[par][kk2] + ((h2)*2+j2)*1024); } while (0)
// one C-quadrant x K=64: 16 MFMA pure burst
#define MFQ(ih, jh) do { _Pragma("unroll") for (int kk2 = 0; kk2 < 2; ++kk2) \
    _Pragma("unroll") for (int i2 = 0; i2 < 4; ++i2) \
    _Pragma("unroll") for (int j2 = 0; j2 < 2; ++j2) \
        acc[(ih)*4+i2][(jh)*2+j2] = __builtin_amdgcn_mfma_f32_16x16x32_bf16( \
            af[(ih)*4+i2][kk2], bfr[(jh)*2+j2][kk2], acc[(ih)*4+i2][(jh)*2+j2], 0, 0, 0); } while (0)

__global__ __launch_bounds__(512, 2) void gemm_lstm(
        const bf16* __restrict__ Ax, int ldx, int ksplit,
        const bf16* __restrict__ Ah, int ldh_in,
        const bf16* __restrict__ W,
        const float* __restrict__ Bp,
        float* __restrict__ cst,
        bf16* __restrict__ hdst, int ldh_out, int offh,
        float* __restrict__ outf, int en_out,
        int K) {
    extern __shared__ __attribute__((aligned(16))) bf16 sh[];   // 131072 B

    const int tid  = threadIdx.x;
    const int lane = tid & 63;
    const int wave = tid >> 6;              // 0..7
    const int wm   = wave >> 2, wn = wave & 3;

    // T1: XCD-aware bijective swizzle (grid 8x50 = 400 blocks, x fastest)
    const int p0g = blockIdx.y * 8 + blockIdx.x;
    const int lb  = (p0g & 7) * 50 + (p0g >> 3);
    const int bn  = lb & 7;                 // gate-col block
    const int bm  = lb >> 3;                // row block

    const int r = lane & 15, q = lane >> 4;
    const int NITER = K >> 7;               // 2 K-tiles per iteration

    f32x4 acc[8][4];
#pragma unroll
    for (int i = 0; i < 8; ++i)
#pragma unroll
        for (int j = 0; j < 4; ++j)
#pragma unroll
            for (int rr = 0; rr < 4; ++rr) acc[i][j][rr] = 0.f;

    // staging geometry: chunk ch = c*512+tid; row = ch>>3 in [0,128);
    // global k-chunk = (ch&7)^(row&7); LDS dest linear (ch*8 elements)
    int srow[2], scol[2];
#pragma unroll
    for (int c = 0; c < 2; ++c) {
        int ch = c * 512 + tid;
        srow[c] = ch >> 3;
        scol[c] = ((ch & 7) ^ (srow[c] & 7)) * 8;
    }

    // 8 LDS read-base pointers: [parity][kk]; all frag reads use imm offsets
    const bf16* adrA[2][2];
    const bf16* adrB[2][2];
#pragma unroll
    for (int par = 0; par < 2; ++par)
#pragma unroll
        for (int kk = 0; kk < 2; ++kk) {
            int x = ((q + 4 * kk) ^ (r & 7)) * 8;
            adrA[par][kk] = sh + par * 32768 + wm * 8192 + r * 64 + x;
            adrB[par][kk] = sh + par * 32768 + 16384 + (wn >> 1) * 8192 + (wn & 1) * 4096
                               + r * 64 + x;
        }

    auto stage_half_A = [&](int tile, int half) {
        int kb = tile << 6;
        const bf16* src; int ld, ko;
        if (kb < ksplit) { src = Ax; ld = ldx;    ko = kb; }
        else             { src = Ah; ld = ldh_in; ko = kb - ksplit; }
        src += (size_t)(bm * BM + half * 128) * ld;
        bf16* dst = sh + (tile & 1) * 32768 + half * 8192;
#pragma unroll
        for (int c = 0; c < 2; ++c)
            gl_lds16(src + (size_t)srow[c] * ld + ko + scol[c],
                     dst + (c * 512 + tid) * 8);
    };
    auto stage_half_B = [&](int tile, int half) {
        const bf16* src = W + (size_t)(bn * BN + half * 128) * K + (tile << 6);
        bf16* dst = sh + (tile & 1) * 32768 + 16384 + half * 8192;
#pragma unroll
        for (int c = 0; c < 2; ++c)
            gl_lds16(src + (size_t)srow[c] * K + scol[c],
                     dst + (c * 512 + tid) * 8);
    };

    // prologue: tile0 A+B, tile1 B (12 loads); confirm tile 0 (4 newest fly)
    stage_half_A(0, 0); stage_half_A(0, 1);
    stage_half_B(0, 0); stage_half_B(0, 1);
    stage_half_B(1, 0); stage_half_B(1, 1);
    VMC(4);
    BAR();

    bf16x8 af[8][2], bfr[4][2];
    for (int it = 0; it < NITER; ++it) {
        const int u = it * 2;
        const bool nlast = (it + 1 < NITER);

        // ---- ph1: A0-3(p0)+B0-1(p0); stage A-lo(u+1)
        DSA(0, 0); DSB(0, 0);
        stage_half_A(u + 1, 0);
        BAR(); LGKM0();
        SP1; MFQ(0, 0); SP0;
        BAR();
        // ---- ph2: B2-3(p0); stage A-hi(u+1)
        DSB(1, 0);
        stage_half_A(u + 1, 1);
        BAR(); LGKM0();
        SP1; MFQ(0, 1); SP0;
        BAR();
        // ---- ph3: A4-7(p0); stage B-lo(u+2)
        DSA(1, 0);
        if (nlast) stage_half_B(u + 2, 0);
        BAR(); LGKM0();
        SP1; MFQ(1, 0); SP0;
        BAR();
        // ---- ph4: stage B-hi(u+2); counted vmcnt confirms tile u+1
        if (nlast) stage_half_B(u + 2, 1);
        BAR(); LGKM0();
        SP1; MFQ(1, 1); SP0;
        if (nlast) { VMC(4); } else { VMC(0); }
        BAR();
        // ---- ph5: A0-3(p1)+B0-1(p1); stage A-lo(u+2)
        DSA(0, 1); DSB(0, 1);
        if (nlast) stage_half_A(u + 2, 0);
        BAR(); LGKM0();
        SP1; MFQ(0, 0); SP0;
        BAR();
        // ---- ph6: B2-3(p1); stage A-hi(u+2)
        DSB(1, 1);
        if (nlast) stage_half_A(u + 2, 1);
        BAR(); LGKM0();
        SP1; MFQ(0, 1); SP0;
        BAR();
        // ---- ph7: A4-7(p1); stage B-lo(u+3)
        DSA(1, 1);
        if (nlast) stage_half_B(u + 3, 0);
        BAR(); LGKM0();
        SP1; MFQ(1, 0); SP0;
        BAR();
        // ---- ph8: stage B-hi(u+3); counted vmcnt confirms tile u+2
        if (nlast) stage_half_B(u + 3, 1);
        BAR(); LGKM0();
        SP1; MFQ(1, 1); SP0;
        if (nlast) VMC(4);
        BAR();
    }
    __syncthreads();   // loop fully drained; LDS reusable as h-xpose buffer

    // ---- fused LSTM epilogue ----
    // C/D mapping (m89/m91-verified): col = lane&15, row = (lane>>4)*4 + reg
    const int colb = bn * BN + wn * 64;
    const int u    = (bn * 4 + wn) * 16 + r;       // global unit index 0..511
    const float bi  = Bp[colb + r];
    const float bff = Bp[colb + 16 + r];
    const float bg  = Bp[colb + 32 + r];
    const float bo  = Bp[colb + 48 + r];

    float cc[8][4];
#pragma unroll
    for (int i = 0; i < 8; ++i)
#pragma unroll
        for (int rr = 0; rr < 4; ++rr) {
            int row = bm * BM + wm * 128 + i * 16 + q * 4 + rr;
            cc[i][rr] = cst[(size_t)row * RNN + u];
        }

#define HLD 72   // h-xpose row stride: 144B rows (16B-aligned)
#pragma unroll
    for (int i = 0; i < 8; ++i) {
#pragma unroll
        for (int rr = 0; rr < 4; ++rr) {
            int rowl = wm * 128 + i * 16 + q * 4 + rr;       // row in block
            int row  = bm * BM + rowl;
            size_t cidx = (size_t)row * RNN + u;
            float gi = acc[i][0][rr] + bi;
            float gf = acc[i][1][rr] + bff;
            float gg = acc[i][2][rr] + bg;
            float go = acc[i][3][rr] + bo;
            float cn = sigmoidf_(gf) * cc[i][rr] + sigmoidf_(gi) * tanhf_(gg);
            float h  = sigmoidf_(go) * tanhf_(cn);
            cst[cidx] = cn;
            if (en_out) outf[cidx] = h;
            sh[rowl * HLD + wn * 16 + r] = __float2bfloat16(h);
        }
    }
    __syncthreads();

    // coalesced h stores: 256 rows x 64 units bf16; 16B x 2048 chunks
#pragma unroll
    for (int hh = 0; hh < 4; ++hh) {
        int t2   = hh * 512 + tid;         // 0..2047
        int rowl = t2 >> 3;                // 0..255
        int c8   = (t2 & 7) * 8;           // 0..56
        uint4 v  = *(const uint4*)&sh[rowl * HLD + c8];
        int row  = bm * BM + rowl;
        int gcol = bn * 64 + c8;           // unit col within [0,512)
        *(uint4*)&hdst[(size_t)row * ldh_out + offh + gcol] = v;
    }
#undef HLD
}

// ---------------------------------------------------------------------------
// Workspace layout (all 16B-aligned; total 122,568,704 B):
//   c1   fp32 [12800][512]   off 0              (26,214,400)
//   c2   fp32 [12800][512]   off  26,214,400    (26,214,400)
//   A2a  bf16 [12800][1024]  off  52,428,800    (26,214,400)
//   A2b  bf16 [12800][1024]  off  78,643,200    (26,214,400)
//   Xbuf bf16 [12800][384]   off 104,857,600    ( 9,830,400)
//   Wc1  bf16 [2048][896]    off 114,688,000    ( 3,670,016)
//   Wc2  bf16 [2048][1024]   off 118,358,016    ( 4,194,304)
//   Bp1  fp32 [2048]         off 122,552,320    (     8,192)
//   Bp2  fp32 [2048]         off 122,560,512    (     8,192)
// First 104,857,600 B (c1,c2,A2a,A2b) zeroed each call: c(-1)=0, h(-1)=0.
// Ping-pong unchanged: L1(t) reads A2[prv][0,512), writes A2[cur][0,512);
// L2(t) reads A2[cur], writes A2[prv][512,1024). No dispatch reads and
// writes the same buffer.
// ---------------------------------------------------------------------------
extern "C" void kernel_launch(void* const* d_in, const int* in_sizes, int n_in,
                              void* d_out, int out_size, void* d_ws, size_t ws_size,
                              hipStream_t stream) {
    (void)in_sizes; (void)n_in; (void)out_size; (void)ws_size;
    const int*   sent = (const int*)d_in[0];
    const float* w2v  = (const float*)d_in[1];
    const float* Wih1 = (const float*)d_in[2];
    const float* Whh1 = (const float*)d_in[3];
    const float* bih1 = (const float*)d_in[4];
    const float* bhh1 = (const float*)d_in[5];
    const float* Wih2 = (const float*)d_in[6];
    const float* Whh2 = (const float*)d_in[7];
    const float* bih2 = (const float*)d_in[8];
    const float* bhh2 = (const float*)d_in[9];
    float* out = (float*)d_out;

    char* ws = (char*)d_ws;
    float* c1   = (float*)(ws);
    float* c2   = (float*)(ws + 26214400);
    bf16*  A2[2];
    A2[0] = (bf16*)(ws + 52428800);
    A2[1] = (bf16*)(ws + 78643200);
    bf16*  Xbuf = (bf16*) (ws + 104857600);
    bf16*  Wc1  = (bf16*) (ws + 114688000);
    bf16*  Wc2  = (bf16*) (ws + 118358016);
    float* Bp1  = (float*)(ws + 122552320);
    float* Bp2  = (float*)(ws + 122560512);

    // one-time: allow 128 KiB dynamic LDS for the GEMM kernel
    static int shmem_set = 0;
    if (!shmem_set) {
        (void)hipFuncSetAttribute((const void*)gemm_lstm,
                                  hipFuncAttributeMaxDynamicSharedMemorySize, 131072);
        shmem_set = 1;
    }

    // zero c1,c2,A2a,A2b (ws is re-poisoned 0xAA before every call)
    hipMemsetAsync(ws, 0, 104857600, stream);

    convert_weights<<<dim3((NG * K2 + 255) / 256), dim3(256), 0, stream>>>(
        Wih1, Whh1, Wih2, Whh2, bih1, bhh1, bih2, bhh2, Wc1, Wc2, Bp1, Bp2);

    for (int t = 0; t < TSTEPS; ++t) {
        const int cur = t & 1, prv = cur ^ 1;

        // x_t -> Xbuf (cols 300..383 zeroed)
        embed_step<<<dim3(BROWS), dim3(EMBP), 0, stream>>>(sent, w2v, Xbuf, t);

        // layer 1: gates = [x_t | h1(t-1)] @ Wc1^T, fused update
        gemm_lstm<<<dim3(NG / BN, BROWS / BM), dim3(512), 131072, stream>>>(
            Xbuf, EMBP, EMBP,
            A2[prv], K2,
            Wc1, Bp1, c1,
            A2[cur], K2, 0,
            (float*)nullptr, 0, K1);

        // layer 2: gates = [h1(t) | h2(t-1)] @ Wc2^T, fused update
        gemm_lstm<<<dim3(NG / BN, BROWS / BM), dim3(512), 131072, stream>>>(
            (const bf16*)nullptr, 0, 0,
            A2[cur], K2,
            Wc2, Bp2, c2,
            A2[prv], K2, RNN,
            out, (t == TSTEPS - 1) ? 1 : 0, K2);
    }
}